// Round 2
// 844.279 us; speedup vs baseline: 1.0675x; 1.0675x over previous
//
#include <hip/hip_runtime.h>
#include <math.h>

#define NB 16
#define HH 80
#define WW 60
#define HWSZ (HH * WW)        // 4800
#define CC 256
#define MTOT (NB * HWSZ)      // 76800
#define KVF (16 * 8 * 32 * 32)
#define KSF (16 * 8 * 32)
#define BUF ((size_t)MTOT * CC)   // 19,660,800 elements

typedef unsigned short u16;
typedef __attribute__((ext_vector_type(8))) short short8;
typedef __attribute__((ext_vector_type(4))) float floatx4;

__device__ __forceinline__ float bf2f(u16 u) {
    union { unsigned int i; float f; } v; v.i = ((unsigned int)u) << 16; return v.f;
}
__device__ __forceinline__ u16 f2bf(float f) {
    union { unsigned int i; float f; } v; v.f = f;
    unsigned int u = v.i;
    u += 0x7FFFu + ((u >> 16) & 1u);          // round-to-nearest-even
    return (u16)(u >> 16);
}
__device__ __forceinline__ float elu1(float x) { return x > 0.f ? x + 1.f : expf(x); }

// PE value for channel c at spatial index l (quirk: div[j] = exp(-2j))
__device__ __forceinline__ float pe_val(int c, int l) {
    const int h = l / WW, w = l - h * WW;
    const int j = c >> 2, sel = c & 3;
    const float dv = expf(-2.0f * (float)j);
    const float pos = (sel < 2) ? (float)(w + 1) : (float)(h + 1);
    const float arg = pos * dv;
    return (sel & 1) ? cosf(arg) : sinf(arg);
}

// ---------------- PE add + [N,C,HW] -> [N,HW,C]; fp32 out optional, bf16 out always ----------------
__global__ __launch_bounds__(256) void add_pe_transpose(const float* __restrict__ in,
                                                        float* __restrict__ outf,
                                                        u16* __restrict__ outb)
{
    __shared__ float tile[32][33];
    const int n = blockIdx.z;
    const int c0 = blockIdx.y * 32;
    const int l0 = blockIdx.x * 32;
    const int tx = threadIdx.x, ty = threadIdx.y;
#pragma unroll
    for (int i = 0; i < 4; ++i) {
        const int cl = ty + i * 8;
        tile[cl][tx] = in[(size_t)n * CC * HWSZ + (size_t)(c0 + cl) * HWSZ + l0 + tx];
    }
    __syncthreads();
#pragma unroll
    for (int i = 0; i < 4; ++i) {
        const int ll = ty + i * 8;
        const int l = l0 + ll;
        const int c = c0 + tx;
        const float val = tile[tx][ll] + pe_val(c, l);
        const size_t idx = ((size_t)n * HWSZ + l) * CC + c;
        if (outf) outf[idx] = val;
        outb[idx] = f2bf(val);
    }
}

// ---------------- [N,HW,C] fp32 -> [N,C,HW] fp32 ----------------
__global__ __launch_bounds__(256) void out_transpose(const float* __restrict__ in,
                                                     float* __restrict__ out)
{
    __shared__ float tile[32][33];
    const int n = blockIdx.z;
    const int c0 = blockIdx.y * 32;
    const int l0 = blockIdx.x * 32;
    const int tx = threadIdx.x, ty = threadIdx.y;
#pragma unroll
    for (int i = 0; i < 4; ++i) {
        const int ll = ty + i * 8;
        tile[ll][tx] = in[((size_t)n * HWSZ + l0 + ll) * CC + c0 + tx];
    }
    __syncthreads();
#pragma unroll
    for (int i = 0; i < 4; ++i) {
        const int cl = ty + i * 8;
        out[(size_t)n * CC * HWSZ + (size_t)(c0 + cl) * HWSZ + l0 + tx] = tile[tx][cl];
    }
}

// ---------------- weight fp32 [K,256] -> bf16 transposed [256,K] ----------------
__global__ __launch_bounds__(256) void convert_wt(const float* __restrict__ W,
                                                  u16* __restrict__ WT, int K)
{
    __shared__ float tile[32][33];
    const int k0 = blockIdx.x * 32;
    const int n0 = blockIdx.y * 32;
    const int tx = threadIdx.x, ty = threadIdx.y;
#pragma unroll
    for (int i = 0; i < 4; ++i)
        tile[ty + i * 8][tx] = W[(size_t)(k0 + ty + i * 8) * 256 + n0 + tx];
    __syncthreads();
#pragma unroll
    for (int i = 0; i < 4; ++i)
        WT[(size_t)(n0 + ty + i * 8) * K + k0 + tx] = f2bf(tile[tx][ty + i * 8]);
}

// ---------------- zero small buffer ----------------
__global__ __launch_bounds__(256) void zero_kernel(float* __restrict__ p, int n)
{
    const int i = blockIdx.x * 256 + threadIdx.x;
    if (i < n) p[i] = 0.f;
}

// ---------------- MFMA GEMM: C_bf16[M,256] = act( [A0|A1][M,K]_bf16 @ W[K,256] ) ----------------
__global__ __launch_bounds__(256) void gemm_mfma(const u16* __restrict__ A0,
                                                 const u16* __restrict__ A1,
                                                 const u16* __restrict__ WT,
                                                 u16* __restrict__ C,
                                                 int K, int relu)
{
    __shared__ u16 As[128 * 32];
    __shared__ u16 Bs[128 * 32];
    const int t = threadIdx.x;
    const int row0 = blockIdx.y * 128;
    const int col0 = blockIdx.x * 128;
    const int w = t >> 6, lane = t & 63;
    const int wr = (w >> 1) * 64, wc = (w & 1) * 64;
    const int quad = lane >> 4, lrow = lane & 15;
    const int sm = t >> 2, skc = (t & 3) * 8;

    const floatx4 zero = {0.f, 0.f, 0.f, 0.f};
    floatx4 acc[4][4];
#pragma unroll
    for (int i = 0; i < 4; ++i)
#pragma unroll
        for (int j = 0; j < 4; ++j) acc[i][j] = zero;

    const size_t arow0 = (size_t)(row0 + sm) * 256 + skc;
    const size_t arow1 = (size_t)(row0 + 64 + sm) * 256 + skc;
    const size_t brow0 = (size_t)(col0 + sm) * K + skc;
    const size_t brow1 = (size_t)(col0 + 64 + sm) * K + skc;

    uint4 ra0 = *(const uint4*)(A0 + arow0);
    uint4 ra1 = *(const uint4*)(A0 + arow1);
    uint4 rb0 = *(const uint4*)(WT + brow0);
    uint4 rb1 = *(const uint4*)(WT + brow1);

    for (int k0 = 0; k0 < K; k0 += 32) {
        __syncthreads();
        *(uint4*)&As[sm * 32 + skc] = ra0;
        *(uint4*)&As[(64 + sm) * 32 + skc] = ra1;
        *(uint4*)&Bs[sm * 32 + skc] = rb0;
        *(uint4*)&Bs[(64 + sm) * 32 + skc] = rb1;
        __syncthreads();
        const int kn = k0 + 32;
        if (kn < K) {
            const u16* Abn = (A1 != nullptr && kn >= 256) ? (A1 + (kn - 256)) : (A0 + kn);
            ra0 = *(const uint4*)(Abn + arow0);
            ra1 = *(const uint4*)(Abn + arow1);
            rb0 = *(const uint4*)(WT + brow0 + kn);
            rb1 = *(const uint4*)(WT + brow1 + kn);
        }
        short8 af[4], bfv[4];
#pragma unroll
        for (int i = 0; i < 4; ++i) {
            af[i]  = *(const short8*)&As[(wr + i * 16 + lrow) * 32 + quad * 8];
            bfv[i] = *(const short8*)&Bs[(wc + i * 16 + lrow) * 32 + quad * 8];
        }
#pragma unroll
        for (int i = 0; i < 4; ++i)
#pragma unroll
            for (int j = 0; j < 4; ++j)
                acc[i][j] = __builtin_amdgcn_mfma_f32_16x16x32_bf16(af[i], bfv[j], acc[i][j], 0, 0, 0);
    }

#pragma unroll
    for (int i = 0; i < 4; ++i) {
        const int rbase = row0 + wr + i * 16 + quad * 4;
#pragma unroll
        for (int j = 0; j < 4; ++j) {
            const int cc = col0 + wc + j * 16 + lrow;
#pragma unroll
            for (int r = 0; r < 4; ++r) {
                float x = acc[i][j][r];
                if (relu) x = fmaxf(x, 0.f);
                C[(size_t)(rbase + r) * 256 + cc] = f2bf(x);
            }
        }
    }
}

// ---------------- KV = sum_s K'[s,d] V'[s,e] ; Ksum[d] = sum_s K'[s,d] (bf16 in) ----------------
#define SCHUNK 480
__global__ __launch_bounds__(256) void kv_kernel(const u16* __restrict__ kbuf,
                                                 const u16* __restrict__ vbuf,
                                                 float* __restrict__ KV,
                                                 float* __restrict__ Ksum)
{
    __shared__ float Kls[16][32];
    __shared__ float Vls[16][32];
    const int n = blockIdx.z, h = blockIdx.y;
    const int s0 = blockIdx.x * SCHUNK;
    const int t = threadIdx.x;
    const int lr = t >> 5;
    const int lc = t & 31;
    const int d = t >> 3;
    const int e0 = (t & 7) * 4;
    const float invS = 1.0f / 4800.0f;
    float acc0 = 0.f, acc1 = 0.f, acc2 = 0.f, acc3 = 0.f, ks = 0.f;
    for (int it = 0; it < SCHUNK / 16; ++it) {
        const int sb = s0 + it * 16;
#pragma unroll
        for (int rr = 0; rr < 2; ++rr) {
            const int s = sb + lr + rr * 8;
            const size_t base = ((size_t)(n * HWSZ + s)) * 256 + h * 32 + lc;
            Kls[lr + rr * 8][lc] = elu1(bf2f(kbuf[base]));
            Vls[lr + rr * 8][lc] = bf2f(vbuf[base]) * invS;
        }
        __syncthreads();
#pragma unroll
        for (int ss = 0; ss < 16; ++ss) {
            const float kval = Kls[ss][d];
            acc0 += kval * Vls[ss][e0 + 0];
            acc1 += kval * Vls[ss][e0 + 1];
            acc2 += kval * Vls[ss][e0 + 2];
            acc3 += kval * Vls[ss][e0 + 3];
            if (e0 == 0) ks += kval;
        }
        __syncthreads();
    }
    float* kvp = KV + ((size_t)(n * 8 + h) * 32 + d) * 32 + e0;
    atomicAdd(kvp + 0, acc0);
    atomicAdd(kvp + 1, acc1);
    atomicAdd(kvp + 2, acc2);
    atomicAdd(kvp + 3, acc3);
    if (e0 == 0) atomicAdd(&Ksum[(size_t)(n * 8 + h) * 32 + d], ks);
}

// ---------------- KV fp32 [n][h][d][e] -> bf16 hi/lo transposed [n][h][e][d] ----------------
__global__ __launch_bounds__(256) void kv_finalize(const float* __restrict__ KV,
                                                   u16* __restrict__ KVThi,
                                                   u16* __restrict__ KVTlo)
{
    const int nh = blockIdx.x;            // 0..127 = n*8+h
    const int t = threadIdx.x;            // 256
    const int d = t >> 3, e0 = (t & 7) * 4;
    const float4 v = *(const float4*)&KV[(size_t)nh * 1024 + d * 32 + e0];
    const float vv[4] = {v.x, v.y, v.z, v.w};
#pragma unroll
    for (int j = 0; j < 4; ++j) {
        const int e = e0 + j;
        const float x = vv[j];
        const u16 hi = f2bf(x);
        const float lo = x - bf2f(hi);
        KVThi[(size_t)nh * 1024 + e * 32 + d] = hi;
        KVTlo[(size_t)nh * 1024 + e * 32 + d] = f2bf(lo);
    }
}

// ---------------- attention apply v3: per-head MFMA, in-place on q ----------------
// out[r][h*32+e] = (sum_d Q'[r][h*32+d] * KV[n][h][d][e]) * 4800 / (1e-6 + Q'row . Ksum[h])
__global__ __launch_bounds__(256) void attn_apply(u16* __restrict__ q,
                                                  const u16* __restrict__ KVThi,
                                                  const u16* __restrict__ KVTlo,
                                                  const float* __restrict__ Ksum)
{
    const int t = threadIdx.x;
    const int row0b = blockIdx.x * 64;            // 4800 % 64 == 0 -> block within one n
    const int n = row0b / HWSZ;
    const int w = t >> 6, lane = t & 63;
    const int quad = lane >> 4, lrow = lane & 15;
    const int row0 = row0b + w * 16;              // 16 rows per wave

    __shared__ float Ks[256];
    Ks[t] = Ksum[(size_t)n * 256 + t];
    __syncthreads();

    const floatx4 zero = {0.f, 0.f, 0.f, 0.f};
#pragma unroll
    for (int h = 0; h < 8; ++h) {
        // ---- A fragment: rows row0+lrow, k = quad*8..quad*8+7 of head h, elu applied
        const size_t qoff = (size_t)(row0 + lrow) * 256 + h * 32 + quad * 8;
        const ushort4 u0 = *(const ushort4*)&q[qoff];
        const ushort4 u1 = *(const ushort4*)&q[qoff + 4];
        float qf[8];
        qf[0] = elu1(bf2f(u0.x)); qf[1] = elu1(bf2f(u0.y));
        qf[2] = elu1(bf2f(u0.z)); qf[3] = elu1(bf2f(u0.w));
        qf[4] = elu1(bf2f(u1.x)); qf[5] = elu1(bf2f(u1.y));
        qf[6] = elu1(bf2f(u1.z)); qf[7] = elu1(bf2f(u1.w));
        short8 a;
#pragma unroll
        for (int j = 0; j < 8; ++j) a[j] = (short)f2bf(qf[j]);

        // ---- zden = Q'row . Ksum[h], computed once per row (fp32)
        float zp = 0.f;
#pragma unroll
        for (int j = 0; j < 8; ++j) zp += qf[j] * Ks[h * 32 + quad * 8 + j];
        zp += __shfl_xor(zp, 16, 64);
        zp += __shfl_xor(zp, 32, 64);
        // now lanes with (lane&15)==r hold full zden for row row0+r

        // ---- B fragments: KV^T bf16 hi/lo, col = e, k-contiguous d
        const size_t kvb = (size_t)(n * 8 + h) * 32;
        const short8 bh0 = *(const short8*)&KVThi[(kvb + lrow) * 32 + quad * 8];
        const short8 bh1 = *(const short8*)&KVThi[(kvb + 16 + lrow) * 32 + quad * 8];
        const short8 bl0 = *(const short8*)&KVTlo[(kvb + lrow) * 32 + quad * 8];
        const short8 bl1 = *(const short8*)&KVTlo[(kvb + 16 + lrow) * 32 + quad * 8];

        floatx4 acc0 = __builtin_amdgcn_mfma_f32_16x16x32_bf16(a, bh0, zero, 0, 0, 0);
        acc0 = __builtin_amdgcn_mfma_f32_16x16x32_bf16(a, bl0, acc0, 0, 0, 0);
        floatx4 acc1 = __builtin_amdgcn_mfma_f32_16x16x32_bf16(a, bh1, zero, 0, 0, 0);
        acc1 = __builtin_amdgcn_mfma_f32_16x16x32_bf16(a, bl1, acc1, 0, 0, 0);

        // ---- scale + store (C layout: row = quad*4+r, col = lrow / 16+lrow)
#pragma unroll
        for (int r = 0; r < 4; ++r) {
            const float zden = __shfl(zp, quad * 4 + r, 64);
            const float sc = 4800.0f / (zden + 1e-6f);
            const size_t ob = (size_t)(row0 + quad * 4 + r) * 256 + h * 32;
            q[ob + lrow]      = f2bf(acc0[r] * sc);
            q[ob + 16 + lrow] = f2bf(acc1[r] * sc);
        }
    }
}

// ---------------- LayerNorm v2: wave-per-row, no barriers ----------------
__device__ __forceinline__ float wave_sum(float v)
{
#pragma unroll
    for (int off = 32; off > 0; off >>= 1) v += __shfl_xor(v, off, 64);
    return v;
}

// 8 rows per wave, 4 waves/block -> 32 rows/block
__global__ __launch_bounds__(256) void ln_inplace(u16* __restrict__ x,
                                                  const float* __restrict__ g,
                                                  const float* __restrict__ b)
{
    const int t = threadIdx.x;
    const int wv = t >> 6, lane = t & 63;
    const int row0 = blockIdx.x * 32 + wv * 8;
    const int c0 = lane * 4;
    const float4 gv = *(const float4*)&g[c0];
    const float4 bv = *(const float4*)&b[c0];
#pragma unroll
    for (int r = 0; r < 8; ++r) {
        const size_t base = (size_t)(row0 + r) * 256 + c0;
        const ushort4 u = *(const ushort4*)&x[base];
        const float v0 = bf2f(u.x), v1 = bf2f(u.y), v2 = bf2f(u.z), v3 = bf2f(u.w);
        const float mu = wave_sum(v0 + v1 + v2 + v3) * (1.0f / 256.0f);
        const float d0 = v0 - mu, d1 = v1 - mu, d2 = v2 - mu, d3 = v3 - mu;
        const float var = wave_sum(d0 * d0 + d1 * d1 + d2 * d2 + d3 * d3) * (1.0f / 256.0f);
        const float rst = rsqrtf(var + 1e-5f);
        ushort4 o;
        o.x = f2bf(d0 * rst * gv.x + bv.x);
        o.y = f2bf(d1 * rst * gv.y + bv.y);
        o.z = f2bf(d2 * rst * gv.z + bv.z);
        o.w = f2bf(d3 * rst * gv.w + bv.w);
        *(ushort4*)&x[base] = o;
    }
}

// LN(x) + residual into fp32 f0, refresh bf16 mirror f0b
__global__ __launch_bounds__(256) void ln_resid(const u16* __restrict__ x,
                                                const float* __restrict__ g,
                                                const float* __restrict__ b,
                                                float* __restrict__ f0,
                                                u16* __restrict__ f0b)
{
    const int t = threadIdx.x;
    const int wv = t >> 6, lane = t & 63;
    const int row0 = blockIdx.x * 32 + wv * 8;
    const int c0 = lane * 4;
    const float4 gv = *(const float4*)&g[c0];
    const float4 bv = *(const float4*)&b[c0];
#pragma unroll
    for (int r = 0; r < 8; ++r) {
        const size_t base = (size_t)(row0 + r) * 256 + c0;
        const ushort4 u = *(const ushort4*)&x[base];
        const float v0 = bf2f(u.x), v1 = bf2f(u.y), v2 = bf2f(u.z), v3 = bf2f(u.w);
        const float mu = wave_sum(v0 + v1 + v2 + v3) * (1.0f / 256.0f);
        const float d0 = v0 - mu, d1 = v1 - mu, d2 = v2 - mu, d3 = v3 - mu;
        const float var = wave_sum(d0 * d0 + d1 * d1 + d2 * d2 + d3 * d3) * (1.0f / 256.0f);
        const float rst = rsqrtf(var + 1e-5f);
        float4 f = *(const float4*)&f0[base];
        f.x += d0 * rst * gv.x + bv.x;
        f.y += d1 * rst * gv.y + bv.y;
        f.z += d2 * rst * gv.z + bv.z;
        f.w += d3 * rst * gv.w + bv.w;
        *(float4*)&f0[base] = f;
        ushort4 o;
        o.x = f2bf(f.x); o.y = f2bf(f.y); o.z = f2bf(f.z); o.w = f2bf(f.w);
        *(ushort4*)&f0b[base] = o;
    }
}

// ---------------- launch ----------------
extern "C" void kernel_launch(void* const* d_in, const int* in_sizes, int n_in,
                              void* d_out, int out_size, void* d_ws, size_t ws_size,
                              hipStream_t stream)
{
    const float* feat0 = (const float*)d_in[0];
    const float* feat1 = (const float*)d_in[1];
    const float* Wq = (const float*)d_in[2];
    const float* Wk = (const float*)d_in[3];
    const float* Wv = (const float*)d_in[4];
    const float* Wm = (const float*)d_in[5];
    const float* W1 = (const float*)d_in[6];
    const float* W2 = (const float*)d_in[7];
    const float* g1 = (const float*)d_in[8];
    const float* b1 = (const float*)d_in[9];
    const float* g2 = (const float*)d_in[10];
    const float* b2 = (const float*)d_in[11];

    float* ws = (float*)d_ws;
    float* KV = ws;
    float* Ksum = KV + KVF;
    u16* Wb = (u16*)(Ksum + KSF);
    const size_t WBE = 458752;
    float* f0 = ws + (KVF + KSF) + WBE;
    u16* f0b = (u16*)(f0 + BUF);
    u16* f1b = f0b + BUF;
    u16* KVThi = f1b + BUF;               // 16*8*32*32 u16 = 256 KB
    u16* KVTlo = KVThi + KVF;             // another 256 KB
    u16* kb16 = (u16*)d_out;
    u16* vb16 = kb16 + BUF;

    const dim3 tb(32, 8);
    const dim3 tgrid(HWSZ / 32, CC / 32, NB);
    add_pe_transpose<<<tgrid, tb, 0, stream>>>(feat0, f0, f0b);
    add_pe_transpose<<<tgrid, tb, 0, stream>>>(feat1, nullptr, f1b);

    for (int i = 0; i < 2; ++i) {
        u16* WqT = Wb + (size_t)i * WBE;
        u16* WkT = WqT + 65536;
        u16* WvT = WkT + 65536;
        u16* WmT = WvT + 65536;
        u16* W1T = WmT + 65536;
        u16* W2T = W1T + 131072;
        convert_wt<<<dim3(8, 8),  tb, 0, stream>>>(Wq + (size_t)i * 65536,  WqT, 256);
        convert_wt<<<dim3(8, 8),  tb, 0, stream>>>(Wk + (size_t)i * 65536,  WkT, 256);
        convert_wt<<<dim3(8, 8),  tb, 0, stream>>>(Wv + (size_t)i * 65536,  WvT, 256);
        convert_wt<<<dim3(8, 8),  tb, 0, stream>>>(Wm + (size_t)i * 65536,  WmT, 256);
        convert_wt<<<dim3(16, 8), tb, 0, stream>>>(W1 + (size_t)i * 131072, W1T, 512);
        convert_wt<<<dim3(8, 8),  tb, 0, stream>>>(W2 + (size_t)i * 65536,  W2T, 256);
    }

    const dim3 ggrid(2, MTOT / 128);
    for (int i = 0; i < 2; ++i) {
        u16* WqT = Wb + (size_t)i * WBE;
        u16* WkT = WqT + 65536;
        u16* WvT = WkT + 65536;
        u16* WmT = WvT + 65536;
        u16* W1T = WmT + 65536;
        u16* W2T = W1T + 131072;

        gemm_mfma<<<ggrid, 256, 0, stream>>>(f1b, nullptr, WkT, kb16, 256, 0);
        gemm_mfma<<<ggrid, 256, 0, stream>>>(f1b, nullptr, WvT, vb16, 256, 0);

        zero_kernel<<<(KVF + KSF + 255) / 256, 256, 0, stream>>>(KV, KVF + KSF);
        kv_kernel<<<dim3(HWSZ / SCHUNK, 8, NB), 256, 0, stream>>>(kb16, vb16, KV, Ksum);
        kv_finalize<<<128, 256, 0, stream>>>(KV, KVThi, KVTlo);

        gemm_mfma<<<ggrid, 256, 0, stream>>>(f0b, nullptr, WqT, kb16, 256, 0);
        attn_apply<<<MTOT / 64, 256, 0, stream>>>(kb16, KVThi, KVTlo, Ksum);

        gemm_mfma<<<ggrid, 256, 0, stream>>>(kb16, nullptr, WmT, vb16, 256, 0);
        ln_inplace<<<MTOT / 32, 256, 0, stream>>>(vb16, g1 + i * 256, b1 + i * 256);

        gemm_mfma<<<ggrid, 256, 0, stream>>>(f0b, vb16, W1T, kb16, 512, 1);
        gemm_mfma<<<ggrid, 256, 0, stream>>>(kb16, nullptr, W2T, vb16, 256, 0);
        ln_resid<<<MTOT / 32, 256, 0, stream>>>(vb16, g2 + i * 256, b2 + i * 256, f0, f0b);
    }

    out_transpose<<<tgrid, tb, 0, stream>>>(f0, (float*)d_out);
}

// Round 3
// 843.067 us; speedup vs baseline: 1.0691x; 1.0014x over previous
//
#include <hip/hip_runtime.h>
#include <math.h>

#define NB 16
#define HH 80
#define WW 60
#define HWSZ (HH * WW)        // 4800
#define CC 256
#define MTOT (NB * HWSZ)      // 76800
#define KVF (16 * 8 * 32 * 32)
#define KSF (16 * 8 * 32)
#define BUF ((size_t)MTOT * CC)   // 19,660,800 elements

typedef unsigned short u16;
typedef __attribute__((ext_vector_type(8))) short short8;
typedef __attribute__((ext_vector_type(4))) float floatx4;

__device__ __forceinline__ float bf2f(u16 u) {
    union { unsigned int i; float f; } v; v.i = ((unsigned int)u) << 16; return v.f;
}
__device__ __forceinline__ u16 f2bf(float f) {
    union { unsigned int i; float f; } v; v.f = f;
    unsigned int u = v.i;
    u += 0x7FFFu + ((u >> 16) & 1u);          // round-to-nearest-even
    return (u16)(u >> 16);
}
__device__ __forceinline__ float elu1(float x) { return x > 0.f ? x + 1.f : expf(x); }

// PE value for channel c at spatial index l (quirk: div[j] = exp(-2j))
__device__ __forceinline__ float pe_val(int c, int l) {
    const int h = l / WW, w = l - h * WW;
    const int j = c >> 2, sel = c & 3;
    const float dv = expf(-2.0f * (float)j);
    const float pos = (sel < 2) ? (float)(w + 1) : (float)(h + 1);
    const float arg = pos * dv;
    return (sel & 1) ? cosf(arg) : sinf(arg);
}

// ---------------- PE add + [N,C,HW] -> [N,HW,C]; fp32 out optional, bf16 out always ----------------
__global__ __launch_bounds__(256) void add_pe_transpose(const float* __restrict__ in,
                                                        float* __restrict__ outf,
                                                        u16* __restrict__ outb)
{
    __shared__ float tile[32][33];
    const int n = blockIdx.z;
    const int c0 = blockIdx.y * 32;
    const int l0 = blockIdx.x * 32;
    const int tx = threadIdx.x, ty = threadIdx.y;
#pragma unroll
    for (int i = 0; i < 4; ++i) {
        const int cl = ty + i * 8;
        tile[cl][tx] = in[(size_t)n * CC * HWSZ + (size_t)(c0 + cl) * HWSZ + l0 + tx];
    }
    __syncthreads();
#pragma unroll
    for (int i = 0; i < 4; ++i) {
        const int ll = ty + i * 8;
        const int l = l0 + ll;
        const int c = c0 + tx;
        const float val = tile[tx][ll] + pe_val(c, l);
        const size_t idx = ((size_t)n * HWSZ + l) * CC + c;
        if (outf) outf[idx] = val;
        outb[idx] = f2bf(val);
    }
}

// ---------------- [N,HW,C] fp32 -> [N,C,HW] fp32 ----------------
__global__ __launch_bounds__(256) void out_transpose(const float* __restrict__ in,
                                                     float* __restrict__ out)
{
    __shared__ float tile[32][33];
    const int n = blockIdx.z;
    const int c0 = blockIdx.y * 32;
    const int l0 = blockIdx.x * 32;
    const int tx = threadIdx.x, ty = threadIdx.y;
#pragma unroll
    for (int i = 0; i < 4; ++i) {
        const int ll = ty + i * 8;
        tile[ll][tx] = in[((size_t)n * HWSZ + l0 + ll) * CC + c0 + tx];
    }
    __syncthreads();
#pragma unroll
    for (int i = 0; i < 4; ++i) {
        const int cl = ty + i * 8;
        out[(size_t)n * CC * HWSZ + (size_t)(c0 + cl) * HWSZ + l0 + tx] = tile[tx][cl];
    }
}

// ---------------- weight fp32 [K,256] -> bf16 transposed [256,K] ----------------
__global__ __launch_bounds__(256) void convert_wt(const float* __restrict__ W,
                                                  u16* __restrict__ WT, int K)
{
    __shared__ float tile[32][33];
    const int k0 = blockIdx.x * 32;
    const int n0 = blockIdx.y * 32;
    const int tx = threadIdx.x, ty = threadIdx.y;
#pragma unroll
    for (int i = 0; i < 4; ++i)
        tile[ty + i * 8][tx] = W[(size_t)(k0 + ty + i * 8) * 256 + n0 + tx];
    __syncthreads();
#pragma unroll
    for (int i = 0; i < 4; ++i)
        WT[(size_t)(n0 + ty + i * 8) * K + k0 + tx] = f2bf(tile[tx][ty + i * 8]);
}

// ---------------- zero small buffer ----------------
__global__ __launch_bounds__(256) void zero_kernel(float* __restrict__ p, int n)
{
    const int i = blockIdx.x * 256 + threadIdx.x;
    if (i < n) p[i] = 0.f;
}

// ---------------- MFMA GEMM: C_bf16[M,256] = act( [A0|A1][M,K]_bf16 @ W[K,256] ) ----------------
__global__ __launch_bounds__(256) void gemm_mfma(const u16* __restrict__ A0,
                                                 const u16* __restrict__ A1,
                                                 const u16* __restrict__ WT,
                                                 u16* __restrict__ C,
                                                 int K, int relu)
{
    __shared__ u16 As[128 * 32];
    __shared__ u16 Bs[128 * 32];
    const int t = threadIdx.x;
    const int row0 = blockIdx.y * 128;
    const int col0 = blockIdx.x * 128;
    const int w = t >> 6, lane = t & 63;
    const int wr = (w >> 1) * 64, wc = (w & 1) * 64;
    const int quad = lane >> 4, lrow = lane & 15;
    const int sm = t >> 2, skc = (t & 3) * 8;

    const floatx4 zero = {0.f, 0.f, 0.f, 0.f};
    floatx4 acc[4][4];
#pragma unroll
    for (int i = 0; i < 4; ++i)
#pragma unroll
        for (int j = 0; j < 4; ++j) acc[i][j] = zero;

    const size_t arow0 = (size_t)(row0 + sm) * 256 + skc;
    const size_t arow1 = (size_t)(row0 + 64 + sm) * 256 + skc;
    const size_t brow0 = (size_t)(col0 + sm) * K + skc;
    const size_t brow1 = (size_t)(col0 + 64 + sm) * K + skc;

    uint4 ra0 = *(const uint4*)(A0 + arow0);
    uint4 ra1 = *(const uint4*)(A0 + arow1);
    uint4 rb0 = *(const uint4*)(WT + brow0);
    uint4 rb1 = *(const uint4*)(WT + brow1);

    for (int k0 = 0; k0 < K; k0 += 32) {
        __syncthreads();
        *(uint4*)&As[sm * 32 + skc] = ra0;
        *(uint4*)&As[(64 + sm) * 32 + skc] = ra1;
        *(uint4*)&Bs[sm * 32 + skc] = rb0;
        *(uint4*)&Bs[(64 + sm) * 32 + skc] = rb1;
        __syncthreads();
        const int kn = k0 + 32;
        if (kn < K) {
            const u16* Abn = (A1 != nullptr && kn >= 256) ? (A1 + (kn - 256)) : (A0 + kn);
            ra0 = *(const uint4*)(Abn + arow0);
            ra1 = *(const uint4*)(Abn + arow1);
            rb0 = *(const uint4*)(WT + brow0 + kn);
            rb1 = *(const uint4*)(WT + brow1 + kn);
        }
        short8 af[4], bfv[4];
#pragma unroll
        for (int i = 0; i < 4; ++i) {
            af[i]  = *(const short8*)&As[(wr + i * 16 + lrow) * 32 + quad * 8];
            bfv[i] = *(const short8*)&Bs[(wc + i * 16 + lrow) * 32 + quad * 8];
        }
#pragma unroll
        for (int i = 0; i < 4; ++i)
#pragma unroll
            for (int j = 0; j < 4; ++j)
                acc[i][j] = __builtin_amdgcn_mfma_f32_16x16x32_bf16(af[i], bfv[j], acc[i][j], 0, 0, 0);
    }

#pragma unroll
    for (int i = 0; i < 4; ++i) {
        const int rbase = row0 + wr + i * 16 + quad * 4;
#pragma unroll
        for (int j = 0; j < 4; ++j) {
            const int cc = col0 + wc + j * 16 + lrow;
#pragma unroll
            for (int r = 0; r < 4; ++r) {
                float x = acc[i][j][r];
                if (relu) x = fmaxf(x, 0.f);
                C[(size_t)(rbase + r) * 256 + cc] = f2bf(x);
            }
        }
    }
}

// ---------------- KV = sum_s K'[s,d] V'[s,e] ; Ksum[d] = sum_s K'[s,d] (bf16 in) ----------------
// v2: 4x4 register blocking, float4 LDS reads, ushort4 staging, cross-wave LDS reduce
#define SCHUNK 480
__global__ __launch_bounds__(256) void kv_kernel(const u16* __restrict__ kbuf,
                                                 const u16* __restrict__ vbuf,
                                                 float* __restrict__ KV,
                                                 float* __restrict__ Ksum)
{
    __shared__ float Kls[32][32];
    __shared__ float Vls[32][32];
    __shared__ float red[4][1024];
    __shared__ float ksred[4][32];
    const int n = blockIdx.z, h = blockIdx.y;
    const int s0 = blockIdx.x * SCHUNK;
    const int t = threadIdx.x;
    const int wv = t >> 6, lane = t & 63;
    const int dg = lane >> 3, eg = lane & 7;
    const int d0 = dg * 4, e0 = eg * 4;
    const int sl = t >> 3;            // staging row 0..31
    const int c0 = (t & 7) * 4;       // staging col 0..28 step 4
    const float invS = 1.0f / 4800.0f;

    float acc[4][4] = {{0.f}};
    float ks[4] = {0.f, 0.f, 0.f, 0.f};

    const size_t sbase = ((size_t)(n * HWSZ + s0 + sl)) * 256 + h * 32 + c0;
    ushort4 kr = *(const ushort4*)&kbuf[sbase];
    ushort4 vr = *(const ushort4*)&vbuf[sbase];

    for (int it = 0; it < SCHUNK / 32; ++it) {
        float4 kf, vf;
        kf.x = elu1(bf2f(kr.x)); kf.y = elu1(bf2f(kr.y));
        kf.z = elu1(bf2f(kr.z)); kf.w = elu1(bf2f(kr.w));
        vf.x = bf2f(vr.x) * invS; vf.y = bf2f(vr.y) * invS;
        vf.z = bf2f(vr.z) * invS; vf.w = bf2f(vr.w) * invS;
        *(float4*)&Kls[sl][c0] = kf;
        *(float4*)&Vls[sl][c0] = vf;
        __syncthreads();
        if (it + 1 < SCHUNK / 32) {
            const size_t nb = sbase + (size_t)(it + 1) * 32 * 256;
            kr = *(const ushort4*)&kbuf[nb];
            vr = *(const ushort4*)&vbuf[nb];
        }
#pragma unroll
        for (int i = 0; i < 8; ++i) {
            const int ss = wv * 8 + i;
            const float4 kq = *(const float4*)&Kls[ss][d0];
            const float4 vq = *(const float4*)&Vls[ss][e0];
            acc[0][0] += kq.x * vq.x; acc[0][1] += kq.x * vq.y;
            acc[0][2] += kq.x * vq.z; acc[0][3] += kq.x * vq.w;
            acc[1][0] += kq.y * vq.x; acc[1][1] += kq.y * vq.y;
            acc[1][2] += kq.y * vq.z; acc[1][3] += kq.y * vq.w;
            acc[2][0] += kq.z * vq.x; acc[2][1] += kq.z * vq.y;
            acc[2][2] += kq.z * vq.z; acc[2][3] += kq.z * vq.w;
            acc[3][0] += kq.w * vq.x; acc[3][1] += kq.w * vq.y;
            acc[3][2] += kq.w * vq.z; acc[3][3] += kq.w * vq.w;
            ks[0] += kq.x; ks[1] += kq.y; ks[2] += kq.z; ks[3] += kq.w;
        }
        __syncthreads();
    }

    // cross-wave reduction in LDS
#pragma unroll
    for (int i = 0; i < 4; ++i) {
        float4 rv;
        rv.x = acc[i][0]; rv.y = acc[i][1]; rv.z = acc[i][2]; rv.w = acc[i][3];
        *(float4*)&red[wv][(d0 + i) * 32 + e0] = rv;
    }
    if (eg == 0) {
#pragma unroll
        for (int i = 0; i < 4; ++i) ksred[wv][d0 + i] = ks[i];
    }
    __syncthreads();

    const float4 r0 = *(const float4*)&red[0][t * 4];
    const float4 r1 = *(const float4*)&red[1][t * 4];
    const float4 r2 = *(const float4*)&red[2][t * 4];
    const float4 r3 = *(const float4*)&red[3][t * 4];
    float* kvp = KV + (size_t)(n * 8 + h) * 1024 + t * 4;
    atomicAdd(kvp + 0, r0.x + r1.x + r2.x + r3.x);
    atomicAdd(kvp + 1, r0.y + r1.y + r2.y + r3.y);
    atomicAdd(kvp + 2, r0.z + r1.z + r2.z + r3.z);
    atomicAdd(kvp + 3, r0.w + r1.w + r2.w + r3.w);
    if (t < 32) {
        const float s = ksred[0][t] + ksred[1][t] + ksred[2][t] + ksred[3][t];
        atomicAdd(&Ksum[(size_t)(n * 8 + h) * 32 + t], s);
    }
}

// ---------------- KV fp32 [n][h][d][e] -> bf16 hi/lo transposed [n][h][e][d] ----------------
__global__ __launch_bounds__(256) void kv_finalize(const float* __restrict__ KV,
                                                   u16* __restrict__ KVThi,
                                                   u16* __restrict__ KVTlo)
{
    const int nh = blockIdx.x;            // 0..127 = n*8+h
    const int t = threadIdx.x;            // 256
    const int d = t >> 3, e0 = (t & 7) * 4;
    const float4 v = *(const float4*)&KV[(size_t)nh * 1024 + d * 32 + e0];
    const float vv[4] = {v.x, v.y, v.z, v.w};
#pragma unroll
    for (int j = 0; j < 4; ++j) {
        const int e = e0 + j;
        const float x = vv[j];
        const u16 hi = f2bf(x);
        const float lo = x - bf2f(hi);
        KVThi[(size_t)nh * 1024 + e * 32 + d] = hi;
        KVTlo[(size_t)nh * 1024 + e * 32 + d] = f2bf(lo);
    }
}

// ---------------- attention apply v3: per-head MFMA, in-place on q ----------------
// out[r][h*32+e] = (sum_d Q'[r][h*32+d] * KV[n][h][d][e]) * 4800 / (1e-6 + Q'row . Ksum[h])
__global__ __launch_bounds__(256) void attn_apply(u16* __restrict__ q,
                                                  const u16* __restrict__ KVThi,
                                                  const u16* __restrict__ KVTlo,
                                                  const float* __restrict__ Ksum)
{
    const int t = threadIdx.x;
    const int row0b = blockIdx.x * 64;            // 4800 % 64 == 0 -> block within one n
    const int n = row0b / HWSZ;
    const int w = t >> 6, lane = t & 63;
    const int quad = lane >> 4, lrow = lane & 15;
    const int row0 = row0b + w * 16;              // 16 rows per wave

    __shared__ float Ks[256];
    Ks[t] = Ksum[(size_t)n * 256 + t];
    __syncthreads();

    const floatx4 zero = {0.f, 0.f, 0.f, 0.f};
#pragma unroll
    for (int h = 0; h < 8; ++h) {
        // ---- A fragment: rows row0+lrow, k = quad*8..quad*8+7 of head h, elu applied
        const size_t qoff = (size_t)(row0 + lrow) * 256 + h * 32 + quad * 8;
        const ushort4 u0 = *(const ushort4*)&q[qoff];
        const ushort4 u1 = *(const ushort4*)&q[qoff + 4];
        float qf[8];
        qf[0] = elu1(bf2f(u0.x)); qf[1] = elu1(bf2f(u0.y));
        qf[2] = elu1(bf2f(u0.z)); qf[3] = elu1(bf2f(u0.w));
        qf[4] = elu1(bf2f(u1.x)); qf[5] = elu1(bf2f(u1.y));
        qf[6] = elu1(bf2f(u1.z)); qf[7] = elu1(bf2f(u1.w));
        short8 a;
#pragma unroll
        for (int j = 0; j < 8; ++j) a[j] = (short)f2bf(qf[j]);

        // ---- zden = Q'row . Ksum[h], computed once per row (fp32)
        float zp = 0.f;
#pragma unroll
        for (int j = 0; j < 8; ++j) zp += qf[j] * Ks[h * 32 + quad * 8 + j];
        zp += __shfl_xor(zp, 16, 64);
        zp += __shfl_xor(zp, 32, 64);
        // now lanes with (lane&15)==r hold full zden for row row0+r

        // ---- B fragments: KV^T bf16 hi/lo, col = e, k-contiguous d
        const size_t kvb = (size_t)(n * 8 + h) * 32;
        const short8 bh0 = *(const short8*)&KVThi[(kvb + lrow) * 32 + quad * 8];
        const short8 bh1 = *(const short8*)&KVThi[(kvb + 16 + lrow) * 32 + quad * 8];
        const short8 bl0 = *(const short8*)&KVTlo[(kvb + lrow) * 32 + quad * 8];
        const short8 bl1 = *(const short8*)&KVTlo[(kvb + 16 + lrow) * 32 + quad * 8];

        floatx4 acc0 = __builtin_amdgcn_mfma_f32_16x16x32_bf16(a, bh0, zero, 0, 0, 0);
        acc0 = __builtin_amdgcn_mfma_f32_16x16x32_bf16(a, bl0, acc0, 0, 0, 0);
        floatx4 acc1 = __builtin_amdgcn_mfma_f32_16x16x32_bf16(a, bh1, zero, 0, 0, 0);
        acc1 = __builtin_amdgcn_mfma_f32_16x16x32_bf16(a, bl1, acc1, 0, 0, 0);

        // ---- scale + store (C layout: row = quad*4+r, col = lrow / 16+lrow)
#pragma unroll
        for (int r = 0; r < 4; ++r) {
            const float zden = __shfl(zp, quad * 4 + r, 64);
            const float sc = 4800.0f / (zden + 1e-6f);
            const size_t ob = (size_t)(row0 + quad * 4 + r) * 256 + h * 32;
            q[ob + lrow]      = f2bf(acc0[r] * sc);
            q[ob + 16 + lrow] = f2bf(acc1[r] * sc);
        }
    }
}

// ---------------- LayerNorm v2: wave-per-row, no barriers ----------------
__device__ __forceinline__ float wave_sum(float v)
{
#pragma unroll
    for (int off = 32; off > 0; off >>= 1) v += __shfl_xor(v, off, 64);
    return v;
}

// 8 rows per wave, 4 waves/block -> 32 rows/block
__global__ __launch_bounds__(256) void ln_inplace(u16* __restrict__ x,
                                                  const float* __restrict__ g,
                                                  const float* __restrict__ b)
{
    const int t = threadIdx.x;
    const int wv = t >> 6, lane = t & 63;
    const int row0 = blockIdx.x * 32 + wv * 8;
    const int c0 = lane * 4;
    const float4 gv = *(const float4*)&g[c0];
    const float4 bv = *(const float4*)&b[c0];
#pragma unroll
    for (int r = 0; r < 8; ++r) {
        const size_t base = (size_t)(row0 + r) * 256 + c0;
        const ushort4 u = *(const ushort4*)&x[base];
        const float v0 = bf2f(u.x), v1 = bf2f(u.y), v2 = bf2f(u.z), v3 = bf2f(u.w);
        const float mu = wave_sum(v0 + v1 + v2 + v3) * (1.0f / 256.0f);
        const float d0 = v0 - mu, d1 = v1 - mu, d2 = v2 - mu, d3 = v3 - mu;
        const float var = wave_sum(d0 * d0 + d1 * d1 + d2 * d2 + d3 * d3) * (1.0f / 256.0f);
        const float rst = rsqrtf(var + 1e-5f);
        ushort4 o;
        o.x = f2bf(d0 * rst * gv.x + bv.x);
        o.y = f2bf(d1 * rst * gv.y + bv.y);
        o.z = f2bf(d2 * rst * gv.z + bv.z);
        o.w = f2bf(d3 * rst * gv.w + bv.w);
        *(ushort4*)&x[base] = o;
    }
}

// LN(x) + residual into fp32 f0, refresh bf16 mirror f0b
__global__ __launch_bounds__(256) void ln_resid(const u16* __restrict__ x,
                                                const float* __restrict__ g,
                                                const float* __restrict__ b,
                                                float* __restrict__ f0,
                                                u16* __restrict__ f0b)
{
    const int t = threadIdx.x;
    const int wv = t >> 6, lane = t & 63;
    const int row0 = blockIdx.x * 32 + wv * 8;
    const int c0 = lane * 4;
    const float4 gv = *(const float4*)&g[c0];
    const float4 bv = *(const float4*)&b[c0];
#pragma unroll
    for (int r = 0; r < 8; ++r) {
        const size_t base = (size_t)(row0 + r) * 256 + c0;
        const ushort4 u = *(const ushort4*)&x[base];
        const float v0 = bf2f(u.x), v1 = bf2f(u.y), v2 = bf2f(u.z), v3 = bf2f(u.w);
        const float mu = wave_sum(v0 + v1 + v2 + v3) * (1.0f / 256.0f);
        const float d0 = v0 - mu, d1 = v1 - mu, d2 = v2 - mu, d3 = v3 - mu;
        const float var = wave_sum(d0 * d0 + d1 * d1 + d2 * d2 + d3 * d3) * (1.0f / 256.0f);
        const float rst = rsqrtf(var + 1e-5f);
        float4 f = *(const float4*)&f0[base];
        f.x += d0 * rst * gv.x + bv.x;
        f.y += d1 * rst * gv.y + bv.y;
        f.z += d2 * rst * gv.z + bv.z;
        f.w += d3 * rst * gv.w + bv.w;
        *(float4*)&f0[base] = f;
        ushort4 o;
        o.x = f2bf(f.x); o.y = f2bf(f.y); o.z = f2bf(f.z); o.w = f2bf(f.w);
        *(ushort4*)&f0b[base] = o;
    }
}

// ---------------- launch ----------------
extern "C" void kernel_launch(void* const* d_in, const int* in_sizes, int n_in,
                              void* d_out, int out_size, void* d_ws, size_t ws_size,
                              hipStream_t stream)
{
    const float* feat0 = (const float*)d_in[0];
    const float* feat1 = (const float*)d_in[1];
    const float* Wq = (const float*)d_in[2];
    const float* Wk = (const float*)d_in[3];
    const float* Wv = (const float*)d_in[4];
    const float* Wm = (const float*)d_in[5];
    const float* W1 = (const float*)d_in[6];
    const float* W2 = (const float*)d_in[7];
    const float* g1 = (const float*)d_in[8];
    const float* b1 = (const float*)d_in[9];
    const float* g2 = (const float*)d_in[10];
    const float* b2 = (const float*)d_in[11];

    float* ws = (float*)d_ws;
    float* KV = ws;
    float* Ksum = KV + KVF;
    u16* Wb = (u16*)(Ksum + KSF);
    const size_t WBE = 458752;
    float* f0 = ws + (KVF + KSF) + WBE;
    u16* f0b = (u16*)(f0 + BUF);
    u16* f1b = f0b + BUF;
    u16* KVThi = f1b + BUF;               // 16*8*32*32 u16 = 256 KB
    u16* KVTlo = KVThi + KVF;             // another 256 KB
    u16* kb16 = (u16*)d_out;
    u16* vb16 = kb16 + BUF;

    const dim3 tb(32, 8);
    const dim3 tgrid(HWSZ / 32, CC / 32, NB);
    add_pe_transpose<<<tgrid, tb, 0, stream>>>(feat0, f0, f0b);
    add_pe_transpose<<<tgrid, tb, 0, stream>>>(feat1, nullptr, f1b);

    for (int i = 0; i < 2; ++i) {
        u16* WqT = Wb + (size_t)i * WBE;
        u16* WkT = WqT + 65536;
        u16* WvT = WkT + 65536;
        u16* WmT = WvT + 65536;
        u16* W1T = WmT + 65536;
        u16* W2T = W1T + 131072;
        convert_wt<<<dim3(8, 8),  tb, 0, stream>>>(Wq + (size_t)i * 65536,  WqT, 256);
        convert_wt<<<dim3(8, 8),  tb, 0, stream>>>(Wk + (size_t)i * 65536,  WkT, 256);
        convert_wt<<<dim3(8, 8),  tb, 0, stream>>>(Wv + (size_t)i * 65536,  WvT, 256);
        convert_wt<<<dim3(8, 8),  tb, 0, stream>>>(Wm + (size_t)i * 65536,  WmT, 256);
        convert_wt<<<dim3(16, 8), tb, 0, stream>>>(W1 + (size_t)i * 131072, W1T, 512);
        convert_wt<<<dim3(8, 8),  tb, 0, stream>>>(W2 + (size_t)i * 65536,  W2T, 256);
    }

    const dim3 ggrid(2, MTOT / 128);
    for (int i = 0; i < 2; ++i) {
        u16* WqT = Wb + (size_t)i * WBE;
        u16* WkT = WqT + 65536;
        u16* WvT = WkT + 65536;
        u16* WmT = WvT + 65536;
        u16* W1T = WmT + 65536;
        u16* W2T = W1T + 131072;

        gemm_mfma<<<ggrid, 256, 0, stream>>>(f1b, nullptr, WkT, kb16, 256, 0);
        gemm_mfma<<<ggrid, 256, 0, stream>>>(f1b, nullptr, WvT, vb16, 256, 0);

        zero_kernel<<<(KVF + KSF + 255) / 256, 256, 0, stream>>>(KV, KVF + KSF);
        kv_kernel<<<dim3(HWSZ / SCHUNK, 8, NB), 256, 0, stream>>>(kb16, vb16, KV, Ksum);
        kv_finalize<<<128, 256, 0, stream>>>(KV, KVThi, KVTlo);

        gemm_mfma<<<ggrid, 256, 0, stream>>>(f0b, nullptr, WqT, kb16, 256, 0);
        attn_apply<<<MTOT / 64, 256, 0, stream>>>(kb16, KVThi, KVTlo, Ksum);

        gemm_mfma<<<ggrid, 256, 0, stream>>>(kb16, nullptr, WmT, vb16, 256, 0);
        ln_inplace<<<MTOT / 32, 256, 0, stream>>>(vb16, g1 + i * 256, b1 + i * 256);

        gemm_mfma<<<ggrid, 256, 0, stream>>>(f0b, vb16, W1T, kb16, 512, 1);
        gemm_mfma<<<ggrid, 256, 0, stream>>>(kb16, nullptr, W2T, vb16, 256, 0);
        ln_resid<<<MTOT / 32, 256, 0, stream>>>(vb16, g2 + i * 256, b2 + i * 256, f0, f0b);
    }

    out_transpose<<<tgrid, tb, 0, stream>>>(f0, (float*)d_out);
}

// Round 6
// 837.677 us; speedup vs baseline: 1.0759x; 1.0064x over previous
//
#include <hip/hip_runtime.h>
#include <math.h>

#define NB 16
#define HH 80
#define WW 60
#define HWSZ (HH * WW)        // 4800
#define CC 256
#define MTOT (NB * HWSZ)      // 76800
#define KVF (16 * 8 * 32 * 32)
#define KSF (16 * 8 * 32)
#define BUF ((size_t)MTOT * CC)   // 19,660,800 elements

// kv chunking: each block does SCH contiguous rows, all 8 heads
#define KVCH 20               // chunks per n
#define KVSCH 240             // rows per chunk (KVCH*KVSCH = 4800)
#define KVTILES 15            // 16-row tiles per chunk

typedef unsigned short u16;
typedef __attribute__((ext_vector_type(8))) short short8;
typedef __attribute__((ext_vector_type(4))) float floatx4;

__device__ __forceinline__ float bf2f(u16 u) {
    union { unsigned int i; float f; } v; v.i = ((unsigned int)u) << 16; return v.f;
}
__device__ __forceinline__ u16 f2bf(float f) {
    union { unsigned int i; float f; } v; v.f = f;
    unsigned int u = v.i;
    u += 0x7FFFu + ((u >> 16) & 1u);          // round-to-nearest-even
    return (u16)(u >> 16);
}
__device__ __forceinline__ float elu1(float x) { return x > 0.f ? x + 1.f : expf(x); }

// PE value for channel c at spatial index l (quirk: div[j] = exp(-2j))
__device__ __forceinline__ float pe_val(int c, int l) {
    const int h = l / WW, w = l - h * WW;
    const int j = c >> 2, sel = c & 3;
    const float dv = expf(-2.0f * (float)j);
    const float pos = (sel < 2) ? (float)(w + 1) : (float)(h + 1);
    const float arg = pos * dv;
    return (sel & 1) ? cosf(arg) : sinf(arg);
}

// ---------------- PE add + [N,C,HW] -> [N,HW,C]; fp32 out optional, bf16 out always ----------------
__global__ __launch_bounds__(256) void add_pe_transpose(const float* __restrict__ in,
                                                        float* __restrict__ outf,
                                                        u16* __restrict__ outb)
{
    __shared__ float tile[32][33];
    const int n = blockIdx.z;
    const int c0 = blockIdx.y * 32;
    const int l0 = blockIdx.x * 32;
    const int tx = threadIdx.x, ty = threadIdx.y;
#pragma unroll
    for (int i = 0; i < 4; ++i) {
        const int cl = ty + i * 8;
        tile[cl][tx] = in[(size_t)n * CC * HWSZ + (size_t)(c0 + cl) * HWSZ + l0 + tx];
    }
    __syncthreads();
#pragma unroll
    for (int i = 0; i < 4; ++i) {
        const int ll = ty + i * 8;
        const int l = l0 + ll;
        const int c = c0 + tx;
        const float val = tile[tx][ll] + pe_val(c, l);
        const size_t idx = ((size_t)n * HWSZ + l) * CC + c;
        if (outf) outf[idx] = val;
        outb[idx] = f2bf(val);
    }
}

// ---------------- [N,HW,C] fp32 -> [N,C,HW] fp32 ----------------
__global__ __launch_bounds__(256) void out_transpose(const float* __restrict__ in,
                                                     float* __restrict__ out)
{
    __shared__ float tile[32][33];
    const int n = blockIdx.z;
    const int c0 = blockIdx.y * 32;
    const int l0 = blockIdx.x * 32;
    const int tx = threadIdx.x, ty = threadIdx.y;
#pragma unroll
    for (int i = 0; i < 4; ++i) {
        const int ll = ty + i * 8;
        tile[ll][tx] = in[((size_t)n * HWSZ + l0 + ll) * CC + c0 + tx];
    }
    __syncthreads();
#pragma unroll
    for (int i = 0; i < 4; ++i) {
        const int cl = ty + i * 8;
        out[(size_t)n * CC * HWSZ + (size_t)(c0 + cl) * HWSZ + l0 + tx] = tile[tx][cl];
    }
}

// ---------------- weight fp32 [K,256] -> bf16 transposed [256,K] ----------------
__global__ __launch_bounds__(256) void convert_wt(const float* __restrict__ W,
                                                  u16* __restrict__ WT, int K)
{
    __shared__ float tile[32][33];
    const int k0 = blockIdx.x * 32;
    const int n0 = blockIdx.y * 32;
    const int tx = threadIdx.x, ty = threadIdx.y;
#pragma unroll
    for (int i = 0; i < 4; ++i)
        tile[ty + i * 8][tx] = W[(size_t)(k0 + ty + i * 8) * 256 + n0 + tx];
    __syncthreads();
#pragma unroll
    for (int i = 0; i < 4; ++i)
        WT[(size_t)(n0 + ty + i * 8) * K + k0 + tx] = f2bf(tile[tx][ty + i * 8]);
}

// ---------------- MFMA GEMM: C_bf16[M,256] = act( [A0|A1][M,K]_bf16 @ W[K,256] ) ----------------
__global__ __launch_bounds__(256) void gemm_mfma(const u16* __restrict__ A0,
                                                 const u16* __restrict__ A1,
                                                 const u16* __restrict__ WT,
                                                 u16* __restrict__ C,
                                                 int K, int relu)
{
    __shared__ u16 As[128 * 32];
    __shared__ u16 Bs[128 * 32];
    const int t = threadIdx.x;
    const int row0 = blockIdx.y * 128;
    const int col0 = blockIdx.x * 128;
    const int w = t >> 6, lane = t & 63;
    const int wr = (w >> 1) * 64, wc = (w & 1) * 64;
    const int quad = lane >> 4, lrow = lane & 15;
    const int sm = t >> 2, skc = (t & 3) * 8;

    const floatx4 zero = {0.f, 0.f, 0.f, 0.f};
    floatx4 acc[4][4];
#pragma unroll
    for (int i = 0; i < 4; ++i)
#pragma unroll
        for (int j = 0; j < 4; ++j) acc[i][j] = zero;

    const size_t arow0 = (size_t)(row0 + sm) * 256 + skc;
    const size_t arow1 = (size_t)(row0 + 64 + sm) * 256 + skc;
    const size_t brow0 = (size_t)(col0 + sm) * K + skc;
    const size_t brow1 = (size_t)(col0 + 64 + sm) * K + skc;

    uint4 ra0 = *(const uint4*)(A0 + arow0);
    uint4 ra1 = *(const uint4*)(A0 + arow1);
    uint4 rb0 = *(const uint4*)(WT + brow0);
    uint4 rb1 = *(const uint4*)(WT + brow1);

    for (int k0 = 0; k0 < K; k0 += 32) {
        __syncthreads();
        *(uint4*)&As[sm * 32 + skc] = ra0;
        *(uint4*)&As[(64 + sm) * 32 + skc] = ra1;
        *(uint4*)&Bs[sm * 32 + skc] = rb0;
        *(uint4*)&Bs[(64 + sm) * 32 + skc] = rb1;
        __syncthreads();
        const int kn = k0 + 32;
        if (kn < K) {
            const u16* Abn = (A1 != nullptr && kn >= 256) ? (A1 + (kn - 256)) : (A0 + kn);
            ra0 = *(const uint4*)(Abn + arow0);
            ra1 = *(const uint4*)(Abn + arow1);
            rb0 = *(const uint4*)(WT + brow0 + kn);
            rb1 = *(const uint4*)(WT + brow1 + kn);
        }
        short8 af[4], bfv[4];
#pragma unroll
        for (int i = 0; i < 4; ++i) {
            af[i]  = *(const short8*)&As[(wr + i * 16 + lrow) * 32 + quad * 8];
            bfv[i] = *(const short8*)&Bs[(wc + i * 16 + lrow) * 32 + quad * 8];
        }
#pragma unroll
        for (int i = 0; i < 4; ++i)
#pragma unroll
            for (int j = 0; j < 4; ++j)
                acc[i][j] = __builtin_amdgcn_mfma_f32_16x16x32_bf16(af[i], bfv[j], acc[i][j], 0, 0, 0);
    }

#pragma unroll
    for (int i = 0; i < 4; ++i) {
        const int rbase = row0 + wr + i * 16 + quad * 4;
#pragma unroll
        for (int j = 0; j < 4; ++j) {
            const int cc = col0 + wc + j * 16 + lrow;
#pragma unroll
            for (int r = 0; r < 4; ++r) {
                float x = acc[i][j][r];
                if (relu) x = fmaxf(x, 0.f);
                C[(size_t)(rbase + r) * 256 + cc] = f2bf(x);
            }
        }
    }
}

// ---------------- KV partials: all 8 heads per block, contiguous row reads ----------------
// Part[n][chunk][h][d][e] = sum_{s in chunk} K'[s,d] V'[s,e];  PartKs likewise for Ksum
__global__ __launch_bounds__(256) void kv_kernel(const u16* __restrict__ kbuf,
                                                 const u16* __restrict__ vbuf,
                                                 float* __restrict__ Part,
                                                 float* __restrict__ PartKs)
{
    __shared__ float Kls[16][256];
    __shared__ float Vls[16][256];
    const int chunk = blockIdx.x, n = blockIdx.y;
    const int t = threadIdx.x;
    // staging role: rows sr, sr+8; 8 channels at sc
    const int sr = t >> 5;            // 0..7
    const int sc = (t & 31) * 8;      // 0..248
    // compute role: head h, 4d x 8e block
    const int h = t >> 5;             // 0..7
    const int wl = t & 31;
    const int d0 = (wl >> 2) * 4;     // 0,4,..,28
    const int e0 = (wl & 3) * 8;      // 0,8,16,24
    const float invS = 1.0f / 4800.0f;

    float acc[4][8];
#pragma unroll
    for (int i = 0; i < 4; ++i)
#pragma unroll
        for (int j = 0; j < 8; ++j) acc[i][j] = 0.f;
    float ks0 = 0.f, ks1 = 0.f, ks2 = 0.f, ks3 = 0.f;

    const size_t gbase = ((size_t)n * HWSZ + (size_t)chunk * KVSCH) * 256;
    const size_t off0 = (size_t)sr * 256 + sc;
    const size_t off1 = off0 + 8 * 256;

    uint4 k0 = *(const uint4*)(kbuf + gbase + off0);
    uint4 k1 = *(const uint4*)(kbuf + gbase + off1);
    uint4 v0 = *(const uint4*)(vbuf + gbase + off0);
    uint4 v1 = *(const uint4*)(vbuf + gbase + off1);

    for (int tile = 0; tile < KVTILES; ++tile) {
        // unpack staged regs -> LDS (elu for K, *invS for V)
        {
            const u16* p = (const u16*)&k0;
            float4 a, b;
            a.x = elu1(bf2f(p[0])); a.y = elu1(bf2f(p[1])); a.z = elu1(bf2f(p[2])); a.w = elu1(bf2f(p[3]));
            b.x = elu1(bf2f(p[4])); b.y = elu1(bf2f(p[5])); b.z = elu1(bf2f(p[6])); b.w = elu1(bf2f(p[7]));
            *(float4*)&Kls[sr][sc] = a; *(float4*)&Kls[sr][sc + 4] = b;
            p = (const u16*)&k1;
            a.x = elu1(bf2f(p[0])); a.y = elu1(bf2f(p[1])); a.z = elu1(bf2f(p[2])); a.w = elu1(bf2f(p[3]));
            b.x = elu1(bf2f(p[4])); b.y = elu1(bf2f(p[5])); b.z = elu1(bf2f(p[6])); b.w = elu1(bf2f(p[7]));
            *(float4*)&Kls[sr + 8][sc] = a; *(float4*)&Kls[sr + 8][sc + 4] = b;
            p = (const u16*)&v0;
            a.x = bf2f(p[0]) * invS; a.y = bf2f(p[1]) * invS; a.z = bf2f(p[2]) * invS; a.w = bf2f(p[3]) * invS;
            b.x = bf2f(p[4]) * invS; b.y = bf2f(p[5]) * invS; b.z = bf2f(p[6]) * invS; b.w = bf2f(p[7]) * invS;
            *(float4*)&Vls[sr][sc] = a; *(float4*)&Vls[sr][sc + 4] = b;
            p = (const u16*)&v1;
            a.x = bf2f(p[0]) * invS; a.y = bf2f(p[1]) * invS; a.z = bf2f(p[2]) * invS; a.w = bf2f(p[3]) * invS;
            b.x = bf2f(p[4]) * invS; b.y = bf2f(p[5]) * invS; b.z = bf2f(p[6]) * invS; b.w = bf2f(p[7]) * invS;
            *(float4*)&Vls[sr + 8][sc] = a; *(float4*)&Vls[sr + 8][sc + 4] = b;
        }
        __syncthreads();
        if (tile + 1 < KVTILES) {
            const size_t nb = gbase + (size_t)(tile + 1) * 16 * 256;
            k0 = *(const uint4*)(kbuf + nb + off0);
            k1 = *(const uint4*)(kbuf + nb + off1);
            v0 = *(const uint4*)(vbuf + nb + off0);
            v1 = *(const uint4*)(vbuf + nb + off1);
        }
#pragma unroll
        for (int s = 0; s < 16; ++s) {
            const float4 kq  = *(const float4*)&Kls[s][h * 32 + d0];
            const float4 vq0 = *(const float4*)&Vls[s][h * 32 + e0];
            const float4 vq1 = *(const float4*)&Vls[s][h * 32 + e0 + 4];
            acc[0][0] += kq.x * vq0.x; acc[0][1] += kq.x * vq0.y; acc[0][2] += kq.x * vq0.z; acc[0][3] += kq.x * vq0.w;
            acc[0][4] += kq.x * vq1.x; acc[0][5] += kq.x * vq1.y; acc[0][6] += kq.x * vq1.z; acc[0][7] += kq.x * vq1.w;
            acc[1][0] += kq.y * vq0.x; acc[1][1] += kq.y * vq0.y; acc[1][2] += kq.y * vq0.z; acc[1][3] += kq.y * vq0.w;
            acc[1][4] += kq.y * vq1.x; acc[1][5] += kq.y * vq1.y; acc[1][6] += kq.y * vq1.z; acc[1][7] += kq.y * vq1.w;
            acc[2][0] += kq.z * vq0.x; acc[2][1] += kq.z * vq0.y; acc[2][2] += kq.z * vq0.z; acc[2][3] += kq.z * vq0.w;
            acc[2][4] += kq.z * vq1.x; acc[2][5] += kq.z * vq1.y; acc[2][6] += kq.z * vq1.z; acc[2][7] += kq.z * vq1.w;
            acc[3][0] += kq.w * vq0.x; acc[3][1] += kq.w * vq0.y; acc[3][2] += kq.w * vq0.z; acc[3][3] += kq.w * vq0.w;
            acc[3][4] += kq.w * vq1.x; acc[3][5] += kq.w * vq1.y; acc[3][6] += kq.w * vq1.z; acc[3][7] += kq.w * vq1.w;
            ks0 += kq.x; ks1 += kq.y; ks2 += kq.z; ks3 += kq.w;
        }
        __syncthreads();
    }

    const size_t pbase = ((size_t)(n * KVCH + chunk) * 8 + h) * 1024;
#pragma unroll
    for (int i = 0; i < 4; ++i) {
        float4 w0, w1;
        w0.x = acc[i][0]; w0.y = acc[i][1]; w0.z = acc[i][2]; w0.w = acc[i][3];
        w1.x = acc[i][4]; w1.y = acc[i][5]; w1.z = acc[i][6]; w1.w = acc[i][7];
        *(float4*)&Part[pbase + (d0 + i) * 32 + e0]     = w0;
        *(float4*)&Part[pbase + (d0 + i) * 32 + e0 + 4] = w1;
    }
    if (e0 == 0) {
        float* pk = PartKs + (size_t)(n * KVCH + chunk) * 256 + h * 32 + d0;
        pk[0] = ks0; pk[1] = ks1; pk[2] = ks2; pk[3] = ks3;
    }
}

// ---------------- chunk-sum + Ksum + fp32 -> bf16 hi/lo transposed [n][h][e][d] ----------------
__global__ __launch_bounds__(256) void kv_finalize(const float* __restrict__ Part,
                                                   const float* __restrict__ PartKs,
                                                   u16* __restrict__ KVThi,
                                                   u16* __restrict__ KVTlo,
                                                   float* __restrict__ Ksum)
{
    const int nh = blockIdx.x;            // 0..127 = n*8+h
    const int n = nh >> 3, h = nh & 7;
    const int t = threadIdx.x;            // 256
    const int d = t >> 3, e0 = (t & 7) * 4;
    float4 s = {0.f, 0.f, 0.f, 0.f};
    for (int c = 0; c < KVCH; ++c) {
        const float4 p = *(const float4*)&Part[(((size_t)(n * KVCH + c)) * 8 + h) * 1024 + d * 32 + e0];
        s.x += p.x; s.y += p.y; s.z += p.z; s.w += p.w;
    }
    const float vv[4] = {s.x, s.y, s.z, s.w};
#pragma unroll
    for (int j = 0; j < 4; ++j) {
        const int e = e0 + j;
        const float x = vv[j];
        const u16 hi = f2bf(x);
        const float lo = x - bf2f(hi);
        KVThi[(size_t)nh * 1024 + e * 32 + d] = hi;
        KVTlo[(size_t)nh * 1024 + e * 32 + d] = f2bf(lo);
    }
    if ((t & 7) == 0) {
        float ksv = 0.f;
        for (int c = 0; c < KVCH; ++c)
            ksv += PartKs[((size_t)(n * KVCH + c)) * 256 + h * 32 + d];
        Ksum[(size_t)n * 256 + h * 32 + d] = ksv;
    }
}

// ---------------- attention apply v3: per-head MFMA, in-place on q ----------------
// out[r][h*32+e] = (sum_d Q'[r][h*32+d] * KV[n][h][d][e]) * 4800 / (1e-6 + Q'row . Ksum[h])
__global__ __launch_bounds__(256) void attn_apply(u16* __restrict__ q,
                                                  const u16* __restrict__ KVThi,
                                                  const u16* __restrict__ KVTlo,
                                                  const float* __restrict__ Ksum)
{
    const int t = threadIdx.x;
    const int row0b = blockIdx.x * 64;            // 4800 % 64 == 0 -> block within one n
    const int n = row0b / HWSZ;
    const int w = t >> 6, lane = t & 63;
    const int quad = lane >> 4, lrow = lane & 15;
    const int row0 = row0b + w * 16;              // 16 rows per wave

    __shared__ float Ks[256];
    Ks[t] = Ksum[(size_t)n * 256 + t];
    __syncthreads();

    const floatx4 zero = {0.f, 0.f, 0.f, 0.f};
#pragma unroll
    for (int h = 0; h < 8; ++h) {
        // ---- A fragment: rows row0+lrow, k = quad*8..quad*8+7 of head h, elu applied
        const size_t qoff = (size_t)(row0 + lrow) * 256 + h * 32 + quad * 8;
        const ushort4 u0 = *(const ushort4*)&q[qoff];
        const ushort4 u1 = *(const ushort4*)&q[qoff + 4];
        float qf[8];
        qf[0] = elu1(bf2f(u0.x)); qf[1] = elu1(bf2f(u0.y));
        qf[2] = elu1(bf2f(u0.z)); qf[3] = elu1(bf2f(u0.w));
        qf[4] = elu1(bf2f(u1.x)); qf[5] = elu1(bf2f(u1.y));
        qf[6] = elu1(bf2f(u1.z)); qf[7] = elu1(bf2f(u1.w));
        short8 a;
#pragma unroll
        for (int j = 0; j < 8; ++j) a[j] = (short)f2bf(qf[j]);

        // ---- zden = Q'row . Ksum[h], computed once per row (fp32)
        float zp = 0.f;
#pragma unroll
        for (int j = 0; j < 8; ++j) zp += qf[j] * Ks[h * 32 + quad * 8 + j];
        zp += __shfl_xor(zp, 16, 64);
        zp += __shfl_xor(zp, 32, 64);
        // now lanes with (lane&15)==r hold full zden for row row0+r

        // ---- B fragments: KV^T bf16 hi/lo, col = e, k-contiguous d
        const size_t kvb = (size_t)(n * 8 + h) * 32;
        const short8 bh0 = *(const short8*)&KVThi[(kvb + lrow) * 32 + quad * 8];
        const short8 bh1 = *(const short8*)&KVThi[(kvb + 16 + lrow) * 32 + quad * 8];
        const short8 bl0 = *(const short8*)&KVTlo[(kvb + lrow) * 32 + quad * 8];
        const short8 bl1 = *(const short8*)&KVTlo[(kvb + 16 + lrow) * 32 + quad * 8];

        floatx4 acc0 = __builtin_amdgcn_mfma_f32_16x16x32_bf16(a, bh0, zero, 0, 0, 0);
        acc0 = __builtin_amdgcn_mfma_f32_16x16x32_bf16(a, bl0, acc0, 0, 0, 0);
        floatx4 acc1 = __builtin_amdgcn_mfma_f32_16x16x32_bf16(a, bh1, zero, 0, 0, 0);
        acc1 = __builtin_amdgcn_mfma_f32_16x16x32_bf16(a, bl1, acc1, 0, 0, 0);

        // ---- scale + store (C layout: row = quad*4+r, col = lrow / 16+lrow)
#pragma unroll
        for (int r = 0; r < 4; ++r) {
            const float zden = __shfl(zp, quad * 4 + r, 64);
            const float sc = 4800.0f / (zden + 1e-6f);
            const size_t ob = (size_t)(row0 + quad * 4 + r) * 256 + h * 32;
            q[ob + lrow]      = f2bf(acc0[r] * sc);
            q[ob + 16 + lrow] = f2bf(acc1[r] * sc);
        }
    }
}

// ---------------- LayerNorm v2: wave-per-row, no barriers ----------------
__device__ __forceinline__ float wave_sum(float v)
{
#pragma unroll
    for (int off = 32; off > 0; off >>= 1) v += __shfl_xor(v, off, 64);
    return v;
}

// 8 rows per wave, 4 waves/block -> 32 rows/block
__global__ __launch_bounds__(256) void ln_inplace(u16* __restrict__ x,
                                                  const float* __restrict__ g,
                                                  const float* __restrict__ b)
{
    const int t = threadIdx.x;
    const int wv = t >> 6, lane = t & 63;
    const int row0 = blockIdx.x * 32 + wv * 8;
    const int c0 = lane * 4;
    const float4 gv = *(const float4*)&g[c0];
    const float4 bv = *(const float4*)&b[c0];
#pragma unroll
    for (int r = 0; r < 8; ++r) {
        const size_t base = (size_t)(row0 + r) * 256 + c0;
        const ushort4 u = *(const ushort4*)&x[base];
        const float v0 = bf2f(u.x), v1 = bf2f(u.y), v2 = bf2f(u.z), v3 = bf2f(u.w);
        const float mu = wave_sum(v0 + v1 + v2 + v3) * (1.0f / 256.0f);
        const float d0 = v0 - mu, d1 = v1 - mu, d2 = v2 - mu, d3 = v3 - mu;
        const float var = wave_sum(d0 * d0 + d1 * d1 + d2 * d2 + d3 * d3) * (1.0f / 256.0f);
        const float rst = rsqrtf(var + 1e-5f);
        ushort4 o;
        o.x = f2bf(d0 * rst * gv.x + bv.x);
        o.y = f2bf(d1 * rst * gv.y + bv.y);
        o.z = f2bf(d2 * rst * gv.z + bv.z);
        o.w = f2bf(d3 * rst * gv.w + bv.w);
        *(ushort4*)&x[base] = o;
    }
}

// LN(x) + residual into fp32 f0, refresh bf16 mirror f0b
__global__ __launch_bounds__(256) void ln_resid(const u16* __restrict__ x,
                                                const float* __restrict__ g,
                                                const float* __restrict__ b,
                                                float* __restrict__ f0,
                                                u16* __restrict__ f0b)
{
    const int t = threadIdx.x;
    const int wv = t >> 6, lane = t & 63;
    const int row0 = blockIdx.x * 32 + wv * 8;
    const int c0 = lane * 4;
    const float4 gv = *(const float4*)&g[c0];
    const float4 bv = *(const float4*)&b[c0];
#pragma unroll
    for (int r = 0; r < 8; ++r) {
        const size_t base = (size_t)(row0 + r) * 256 + c0;
        const ushort4 u = *(const ushort4*)&x[base];
        const float v0 = bf2f(u.x), v1 = bf2f(u.y), v2 = bf2f(u.z), v3 = bf2f(u.w);
        const float mu = wave_sum(v0 + v1 + v2 + v3) * (1.0f / 256.0f);
        const float d0 = v0 - mu, d1 = v1 - mu, d2 = v2 - mu, d3 = v3 - mu;
        const float var = wave_sum(d0 * d0 + d1 * d1 + d2 * d2 + d3 * d3) * (1.0f / 256.0f);
        const float rst = rsqrtf(var + 1e-5f);
        float4 f = *(const float4*)&f0[base];
        f.x += d0 * rst * gv.x + bv.x;
        f.y += d1 * rst * gv.y + bv.y;
        f.z += d2 * rst * gv.z + bv.z;
        f.w += d3 * rst * gv.w + bv.w;
        *(float4*)&f0[base] = f;
        ushort4 o;
        o.x = f2bf(f.x); o.y = f2bf(f.y); o.z = f2bf(f.z); o.w = f2bf(f.w);
        *(ushort4*)&f0b[base] = o;
    }
}

// ---------------- launch ----------------
extern "C" void kernel_launch(void* const* d_in, const int* in_sizes, int n_in,
                              void* d_out, int out_size, void* d_ws, size_t ws_size,
                              hipStream_t stream)
{
    const float* feat0 = (const float*)d_in[0];
    const float* feat1 = (const float*)d_in[1];
    const float* Wq = (const float*)d_in[2];
    const float* Wk = (const float*)d_in[3];
    const float* Wv = (const float*)d_in[4];
    const float* Wm = (const float*)d_in[5];
    const float* W1 = (const float*)d_in[6];
    const float* W2 = (const float*)d_in[7];
    const float* g1 = (const float*)d_in[8];
    const float* b1 = (const float*)d_in[9];
    const float* g2 = (const float*)d_in[10];
    const float* b2 = (const float*)d_in[11];

    float* ws = (float*)d_ws;
    float* Ksum = ws;                                       // KSF floats
    float* Part = ws + KSF;                                 // NB*KVCH*8192 floats
    float* PartKs = Part + (size_t)NB * KVCH * 8192;        // NB*KVCH*256 floats
    u16* Wb = (u16*)(PartKs + (size_t)NB * KVCH * 256);
    const size_t WBE = 458752;
    float* f0 = (float*)(Wb + 2 * WBE);
    u16* f0b = (u16*)(f0 + BUF);
    u16* f1b = f0b + BUF;
    u16* KVThi = f1b + BUF;               // 16*8*32*32 u16 = 256 KB
    u16* KVTlo = KVThi + KVF;             // another 256 KB
    u16* kb16 = (u16*)d_out;
    u16* vb16 = kb16 + BUF;

    const dim3 tb(32, 8);
    const dim3 tgrid(HWSZ / 32, CC / 32, NB);
    add_pe_transpose<<<tgrid, tb, 0, stream>>>(feat0, f0, f0b);
    add_pe_transpose<<<tgrid, tb, 0, stream>>>(feat1, nullptr, f1b);

    for (int i = 0; i < 2; ++i) {
        u16* WqT = Wb + (size_t)i * WBE;
        u16* WkT = WqT + 65536;
        u16* WvT = WkT + 65536;
        u16* WmT = WvT + 65536;
        u16* W1T = WmT + 65536;
        u16* W2T = W1T + 131072;
        convert_wt<<<dim3(8, 8),  tb, 0, stream>>>(Wq + (size_t)i * 65536,  WqT, 256);
        convert_wt<<<dim3(8, 8),  tb, 0, stream>>>(Wk + (size_t)i * 65536,  WkT, 256);
        convert_wt<<<dim3(8, 8),  tb, 0, stream>>>(Wv + (size_t)i * 65536,  WvT, 256);
        convert_wt<<<dim3(8, 8),  tb, 0, stream>>>(Wm + (size_t)i * 65536,  WmT, 256);
        convert_wt<<<dim3(16, 8), tb, 0, stream>>>(W1 + (size_t)i * 131072, W1T, 512);
        convert_wt<<<dim3(8, 8),  tb, 0, stream>>>(W2 + (size_t)i * 65536,  W2T, 256);
    }

    const dim3 ggrid(2, MTOT / 128);
    for (int i = 0; i < 2; ++i) {
        u16* WqT = Wb + (size_t)i * WBE;
        u16* WkT = WqT + 65536;
        u16* WvT = WkT + 65536;
        u16* WmT = WvT + 65536;
        u16* W1T = WmT + 65536;
        u16* W2T = W1T + 131072;

        gemm_mfma<<<ggrid, 256, 0, stream>>>(f1b, nullptr, WkT, kb16, 256, 0);
        gemm_mfma<<<ggrid, 256, 0, stream>>>(f1b, nullptr, WvT, vb16, 256, 0);

        kv_kernel<<<dim3(KVCH, NB), 256, 0, stream>>>(kb16, vb16, Part, PartKs);
        kv_finalize<<<128, 256, 0, stream>>>(Part, PartKs, KVThi, KVTlo, Ksum);

        gemm_mfma<<<ggrid, 256, 0, stream>>>(f0b, nullptr, WqT, kb16, 256, 0);
        attn_apply<<<MTOT / 64, 256, 0, stream>>>(kb16, KVThi, KVTlo, Ksum);

        gemm_mfma<<<ggrid, 256, 0, stream>>>(kb16, nullptr, WmT, vb16, 256, 0);
        ln_inplace<<<MTOT / 32, 256, 0, stream>>>(vb16, g1 + i * 256, b1 + i * 256);

        gemm_mfma<<<ggrid, 256, 0, stream>>>(f0b, vb16, W1T, kb16, 512, 1);
        gemm_mfma<<<ggrid, 256, 0, stream>>>(kb16, nullptr, W2T, vb16, 256, 0);
        ln_resid<<<MTOT / 32, 256, 0, stream>>>(vb16, g2 + i * 256, b2 + i * 256, f0, f0b);
    }

    out_transpose<<<tgrid, tb, 0, stream>>>(f0, (float*)d_out);
}